// Round 11
// baseline (51.684 us; speedup 1.0000x reference)
//
#include <hip/hip_runtime.h>
#include <math.h>

// NEAT forward, round 11: two-choice replicated activations.
//  - act stored TWICE in LDS (143,360 B, still 1 block/CU):
//      copy A: neuron i at halves 4i          -> bank-pair class i&15
//      copy B: neuron i at halves 35840+4*jB  -> class (i+(i>>4))&15
//        jB(i) = (i&~15) | ((i+(i>>4))&15)    (bijective per 16-block)
//  - prep assigns each edge to a class window (cap 4) with TWO choices
//    (power-of-two-choices): round 1 A-prefs, round 2 losers try B into
//    residual capacity, rare double-losers spill to holes. Spill rate
//    ~19% -> ~6%, so nearly every gather wave-inst is exactly 4/bank
//    (the b64 conflict-free floor).
//  - record u16 idx encodes the chosen copy: v = i  or  8960 + jB(i);
//    fwd inner loop unchanged (addr = v*8 bytes).
//  - fwd: R9's fmaf form (R10 asm was neutral); writes each new act to
//    both copies (2 ds_write_b64).

#define N_IN    512
#define NLAYER  9
#define DEG     64
#define BATCH   1024
#define BPB     4
#define THREADS 1024
#define TOTAL_N 8960            // 512 + 8*1024 + 256
#define N_OUT   256
#define NEDGE_N 8448            // edge-owning neurons

union H4 { uint2 u; _Float16 h[4]; };
union H2 { unsigned u; _Float16 h[2]; };
union HS { _Float16 h; unsigned short s; };

__device__ __forceinline__ int jswz(int i) {        // copy-B position
    return (i & ~15) | ((i + (i >> 4)) & 15);
}

// ---- prep: one wave per neuron, two-choice window assignment ----
__global__ __launch_bounds__(256)
void neat_prep(const float* __restrict__ wts,
               const int*   __restrict__ sidx,
               uint4*       __restrict__ rec)
{
    __shared__ unsigned sortbuf[4][64];   // 1 KB, one row per wave

    const int tid  = threadIdx.x;
    const int wave = tid >> 6;
    const int lane = tid & 63;
    const int t    = blockIdx.x * 4 + wave;          // neuron 0..8447
    const unsigned long long lt = (1ull << lane) - 1ull;

    const int e   = (t << 6) + lane;                 // coalesced
    const int idx = sidx[e];
    HS w; w.h = (_Float16)wts[e];
    const int cA = idx & 15;
    const int cB = (idx + (idx >> 4)) & 15;

    // round 1: A preferences
    unsigned long long mA[16];
    #pragma unroll
    for (int cc = 0; cc < 16; ++cc) mA[cc] = __ballot(cA == cc);
    const int rankA = (int)__popcll(mA[cA] & lt);
    const bool accA = rankA < 4;

    // round 2: losers try B into residual capacity
    unsigned long long mB[16];
    #pragma unroll
    for (int cc = 0; cc < 16; ++cc) mB[cc] = __ballot(!accA && cB == cc);
    int uAcB = (int)__popcll(mA[cB]); uAcB = uAcB < 4 ? uAcB : 4;
    const int rankB = (int)__popcll(mB[cB] & lt);
    const bool accB = !accA && (rankB < 4 - uAcB);

    const bool placed = accA || accB;
    int slot_pre;
    if (placed) {
        slot_pre = accA ? ((cA << 2) + rankA) : ((cB << 2) + uAcB + rankB);
    } else {
        // spill: match ordinal to hole ordinal over residual capacity
        const unsigned long long msp = __ballot(!placed);
        const int myspill = (int)__popcll(msp & lt);
        int hcum = 0; slot_pre = 0;
        bool found = false;
        #pragma unroll
        for (int cc = 0; cc < 16; ++cc) {
            int uA = (int)__popcll(mA[cc]); uA = uA < 4 ? uA : 4;
            int uB = (int)__popcll(mB[cc]); const int capB = 4 - uA;
            uB = uB < capB ? uB : capB;
            const int used  = uA + uB;
            const int holes = 4 - used;
            const bool take = !found && (myspill < hcum + holes);
            slot_pre = take ? ((cc << 2) + used + (myspill - hcum)) : slot_pre;
            found = found || take;
            hcum += holes;
        }
    }

    // encoded gather index: copy B only when accepted there
    const int v = accB ? (8960 + jswz(idx)) : idx;

    const int fl    = t & 63;                        // fwd lane of this neuron
    const int sigma = ((fl & 15) << 2) | (fl >> 4);  // bijection on 0..63
    const int slot  = (slot_pre + sigma) & 63;
    sortbuf[wave][slot] = (unsigned)v | ((unsigned)w.s << 16);
    __syncthreads();

    if (lane < 16) {                                 // pack 4 slots -> 1 record
        const unsigned s0 = sortbuf[wave][(lane << 2) + 0];
        const unsigned s1 = sortbuf[wave][(lane << 2) + 1];
        const unsigned s2 = sortbuf[wave][(lane << 2) + 2];
        const unsigned s3 = sortbuf[wave][(lane << 2) + 3];
        uint4 o;
        o.x = (s0 & 0xffffu) | (s1 << 16);
        o.y = (s2 & 0xffffu) | (s3 << 16);
        o.z = (s0 >> 16) | (s1 & 0xffff0000u);
        o.w = (s2 >> 16) | (s3 & 0xffff0000u);
        rec[((t >> 6) << 10) + (lane << 6) + fl] = o;
    }
}

__global__ __launch_bounds__(THREADS, 4)
void neat_fwd(const float* __restrict__ in,
              const uint4* __restrict__ rec,
              float*       __restrict__ out)
{
    __shared__ _Float16 act[2 * TOTAL_N * BPB];      // two copies, 143,360 B

    const int tid   = threadIdx.x;
    const int bbase = blockIdx.x * BPB;

    // ---- stage inputs (f32 -> f16), both copies ----
    {
        const float* src = in + bbase * N_IN;
        for (int t = tid; t < BPB * N_IN; t += THREADS) {
            int j = t >> 9;
            int i = t & (N_IN - 1);
            const _Float16 v = (_Float16)src[t];
            act[(i << 2) + j] = v;
            act[((8960 + jswz(i)) << 2) + j] = v;
        }
    }
    __syncthreads();

    int recBase = 0;
    int nb      = N_IN;
    #pragma unroll 1
    for (int layer = 0; layer < NLAYER; ++layer) {
        const int n = (layer < NLAYER - 1) ? 1024 : N_OUT;
        if (tid < n) {
            const int neuron = tid;
            const uint4* rp = rec + recBase + ((neuron >> 6) << 10) + (neuron & 63);

            uint4 r[16];
            #pragma unroll
            for (int q = 0; q < 16; ++q) r[q] = rp[q << 6];

            float accx = 0.f, accy = 0.f, accz = 0.f, accw = 0.f;
            #pragma unroll
            for (int q = 0; q < 16; ++q) {
                const uint4 r4 = r[q];
                H4 g0, g1, g2, g3;
                g0.u = *reinterpret_cast<const uint2*>(act + ((r4.x & 0xffffu) << 2));
                g1.u = *reinterpret_cast<const uint2*>(act + ((r4.x >> 16) << 2));
                g2.u = *reinterpret_cast<const uint2*>(act + ((r4.y & 0xffffu) << 2));
                g3.u = *reinterpret_cast<const uint2*>(act + ((r4.y >> 16) << 2));
                H2 wz, ww; wz.u = r4.z; ww.u = r4.w;
                const float w0 = (float)wz.h[0];
                const float w1 = (float)wz.h[1];
                const float w2 = (float)ww.h[0];
                const float w3 = (float)ww.h[1];
                accx = fmaf((float)g0.h[0], w0, accx);
                accy = fmaf((float)g0.h[1], w0, accy);
                accz = fmaf((float)g0.h[2], w0, accz);
                accw = fmaf((float)g0.h[3], w0, accw);
                accx = fmaf((float)g1.h[0], w1, accx);
                accy = fmaf((float)g1.h[1], w1, accy);
                accz = fmaf((float)g1.h[2], w1, accz);
                accw = fmaf((float)g1.h[3], w1, accw);
                accx = fmaf((float)g2.h[0], w2, accx);
                accy = fmaf((float)g2.h[1], w2, accy);
                accz = fmaf((float)g2.h[2], w2, accz);
                accw = fmaf((float)g2.h[3], w2, accw);
                accx = fmaf((float)g3.h[0], w3, accx);
                accy = fmaf((float)g3.h[1], w3, accy);
                accz = fmaf((float)g3.h[2], w3, accz);
                accw = fmaf((float)g3.h[3], w3, accw);
            }

            float4 sg;
            sg.x = 1.f / (1.f + __expf(-accx));
            sg.y = 1.f / (1.f + __expf(-accy));
            sg.z = 1.f / (1.f + __expf(-accz));
            sg.w = 1.f / (1.f + __expf(-accw));

            if (layer < NLAYER - 1) {
                H4 p;
                p.h[0] = (_Float16)sg.x; p.h[1] = (_Float16)sg.y;
                p.h[2] = (_Float16)sg.z; p.h[3] = (_Float16)sg.w;
                const int no = nb + neuron;
                *reinterpret_cast<uint2*>(act + (no << 2)) = p.u;
                *reinterpret_cast<uint2*>(act + ((8960 + jswz(no)) << 2)) = p.u;
            } else {
                float* op = out + neuron;            // f32 output
                op[(bbase + 0) * N_OUT] = sg.x;
                op[(bbase + 1) * N_OUT] = sg.y;
                op[(bbase + 2) * N_OUT] = sg.z;
                op[(bbase + 3) * N_OUT] = sg.w;
            }
        }
        __syncthreads();
        recBase += n << 4;
        nb      += n;
    }
}

extern "C" void kernel_launch(void* const* d_in, const int* in_sizes, int n_in,
                              void* d_out, int out_size, void* d_ws, size_t ws_size,
                              hipStream_t stream)
{
    const float* in  = (const float*)d_in[0];
    const float* wts = (const float*)d_in[1];
    const int*   sx  = (const int*)d_in[2];
    float*       out = (float*)d_out;
    uint4*       rec = (uint4*)d_ws;    // 135,168 * 16 = 2,162,688 B

    neat_prep<<<NEDGE_N / 4, 256, 0, stream>>>(wts, sx, rec);
    neat_fwd<<<BATCH / BPB, THREADS, 0, stream>>>(in, rec, out);
}

// Round 12
// 48.463 us; speedup vs baseline: 1.0665x; 1.0665x over previous
//
#include <hip/hip_runtime.h>
#include <math.h>

// NEAT forward, round 12.
//  - prep: trivial transpose/convert (R3-style) — one thread = one 16-B
//    record {4x u16 idx, 4x f16 w}, no sort. Cross-round evidence says the
//    bank-sort never moved fwd time (R4 +30% conflicts = +-0; R11 -10% =
//    +-0) but its ballot prep cost ~4.4 us of the total-vs-fwd gap
//    (R3 gap 2.6 us vs R8-R11 ~7.0 us).
//  - fwd: byte-identical to R9 (best measured: 42.4 us, VGPR 32) —
//    f16 act LDS, direct tid=neuron, 16-record register prefetch,
//    fmaf inner loop, f32 output.

#define N_IN    512
#define NLAYER  9
#define DEG     64
#define BATCH   1024
#define BPB     4
#define THREADS 1024
#define TOTAL_N 8960            // 512 + 8*1024 + 256
#define N_OUT   256
#define NREC    135168          // E_TOTAL/4 ; = 528 * 256 exactly

union H4 { uint2 u; _Float16 h[4]; };
union H2 { unsigned u; _Float16 h[2]; };
union HS { _Float16 h; unsigned short s; };

// ---- prep: one thread = one record, no sort ----
__global__ __launch_bounds__(256)
void neat_prep(const float* __restrict__ wts,
               const int*   __restrict__ sidx,
               uint4*       __restrict__ rec)
{
    const int r = blockIdx.x * 256 + threadIdx.x;   // 0..135167, grid exact
    const int l = r >> 14;                          // layer (8 = last)
    const int j = r & 16383;
    const int n = ((j >> 10) << 6) | (j & 63);      // neuron within layer
    const int q = (j >> 6) & 15;                    // quad
    const int e0 = (l << 16) + (n << 6) + (q << 2);

    const int4   s4 = *reinterpret_cast<const int4*>(sidx + e0);
    const float4 w4 = *reinterpret_cast<const float4*>(wts + e0);
    HS h0, h1, h2, h3;
    h0.h = (_Float16)w4.x; h1.h = (_Float16)w4.y;
    h2.h = (_Float16)w4.z; h3.h = (_Float16)w4.w;

    uint4 o;
    o.x = ((unsigned)s4.x & 0xffffu) | ((unsigned)s4.y << 16);
    o.y = ((unsigned)s4.z & 0xffffu) | ((unsigned)s4.w << 16);
    o.z = (unsigned)h0.s | ((unsigned)h1.s << 16);
    o.w = (unsigned)h2.s | ((unsigned)h3.s << 16);
    rec[r] = o;                                     // coalesced
}

__global__ __launch_bounds__(THREADS, 4)
void neat_fwd(const float* __restrict__ in,
              const uint4* __restrict__ rec,
              float*       __restrict__ out)
{
    __shared__ _Float16 act[TOTAL_N * BPB];          // 71,680 B

    const int tid   = threadIdx.x;
    const int bbase = blockIdx.x * BPB;

    // ---- stage inputs (f32 -> f16) ----
    {
        const float* src = in + bbase * N_IN;
        for (int t = tid; t < BPB * N_IN; t += THREADS) {
            int j = t >> 9;
            int i = t & (N_IN - 1);
            act[i * BPB + j] = (_Float16)src[t];
        }
    }
    __syncthreads();

    int recBase = 0;
    int nb      = N_IN;
    #pragma unroll 1
    for (int layer = 0; layer < NLAYER; ++layer) {
        const int n = (layer < NLAYER - 1) ? 1024 : N_OUT;
        if (tid < n) {
            const int neuron = tid;
            const uint4* rp = rec + recBase + ((neuron >> 6) << 10) + (neuron & 63);

            uint4 r[16];
            #pragma unroll
            for (int q = 0; q < 16; ++q) r[q] = rp[q << 6];

            float accx = 0.f, accy = 0.f, accz = 0.f, accw = 0.f;
            #pragma unroll
            for (int q = 0; q < 16; ++q) {
                const uint4 r4 = r[q];
                H4 g0, g1, g2, g3;
                g0.u = *reinterpret_cast<const uint2*>(act + ((r4.x & 0xffffu) << 2));
                g1.u = *reinterpret_cast<const uint2*>(act + ((r4.x >> 16) << 2));
                g2.u = *reinterpret_cast<const uint2*>(act + ((r4.y & 0xffffu) << 2));
                g3.u = *reinterpret_cast<const uint2*>(act + ((r4.y >> 16) << 2));
                H2 wz, ww; wz.u = r4.z; ww.u = r4.w;
                const float w0 = (float)wz.h[0];
                const float w1 = (float)wz.h[1];
                const float w2 = (float)ww.h[0];
                const float w3 = (float)ww.h[1];
                accx = fmaf((float)g0.h[0], w0, accx);
                accy = fmaf((float)g0.h[1], w0, accy);
                accz = fmaf((float)g0.h[2], w0, accz);
                accw = fmaf((float)g0.h[3], w0, accw);
                accx = fmaf((float)g1.h[0], w1, accx);
                accy = fmaf((float)g1.h[1], w1, accy);
                accz = fmaf((float)g1.h[2], w1, accz);
                accw = fmaf((float)g1.h[3], w1, accw);
                accx = fmaf((float)g2.h[0], w2, accx);
                accy = fmaf((float)g2.h[1], w2, accy);
                accz = fmaf((float)g2.h[2], w2, accz);
                accw = fmaf((float)g2.h[3], w2, accw);
                accx = fmaf((float)g3.h[0], w3, accx);
                accy = fmaf((float)g3.h[1], w3, accy);
                accz = fmaf((float)g3.h[2], w3, accz);
                accw = fmaf((float)g3.h[3], w3, accw);
            }

            float4 sg;
            sg.x = 1.f / (1.f + __expf(-accx));
            sg.y = 1.f / (1.f + __expf(-accy));
            sg.z = 1.f / (1.f + __expf(-accz));
            sg.w = 1.f / (1.f + __expf(-accw));

            if (layer < NLAYER - 1) {
                H4 p;
                p.h[0] = (_Float16)sg.x; p.h[1] = (_Float16)sg.y;
                p.h[2] = (_Float16)sg.z; p.h[3] = (_Float16)sg.w;
                *reinterpret_cast<uint2*>(act + ((nb + neuron) << 2)) = p.u;
            } else {
                float* op = out + neuron;            // f32 output
                op[(bbase + 0) * N_OUT] = sg.x;
                op[(bbase + 1) * N_OUT] = sg.y;
                op[(bbase + 2) * N_OUT] = sg.z;
                op[(bbase + 3) * N_OUT] = sg.w;
            }
        }
        __syncthreads();
        recBase += n << 4;
        nb      += n;
    }
}

extern "C" void kernel_launch(void* const* d_in, const int* in_sizes, int n_in,
                              void* d_out, int out_size, void* d_ws, size_t ws_size,
                              hipStream_t stream)
{
    const float* in  = (const float*)d_in[0];
    const float* wts = (const float*)d_in[1];
    const int*   sx  = (const int*)d_in[2];
    float*       out = (float*)d_out;
    uint4*       rec = (uint4*)d_ws;    // 135,168 * 16 = 2,162,688 B

    neat_prep<<<NREC / 256, 256, 0, stream>>>(wts, sx, rec);
    neat_fwd<<<BATCH / BPB, THREADS, 0, stream>>>(in, rec, out);
}